// Round 9
// baseline (148.768 us; speedup 1.0000x reference)
//
#include <hip/hip_runtime.h>
#include <hip/hip_bf16.h>
#include <math.h>

// HungarianMatcher cost matrix, round 9: RPB=16 + nontemporal stores.
// out[row, j] = sum_k |boxes[row][k] - tgt[j][k]| - sigmoid(logits[row])[ids[j]]
// out = [8192, 4096] f32 = 134 MB; write floor ~= 20.5 us @ 6.6 TB/s.
//
// Ladder (kernel-only est., subtracting harness poison fills from dur_us):
//   1 row/blk ~56-77us -> RPB=4 ~41us -> RPB=8+nt ~39us.
// Column-table re-reads: 655 -> 164 -> 82 MB; RPB=16 takes it to 41 MB and
// doubles per-thread store depth (64 float4 stores, better queue pressure).
// Fills hit 6.6 TB/s at 9% occupancy, so ~3 waves/SIMD here is plenty.

#define COLS   4096
#define COLS4  1024        // float4 columns
#define RPB    16          // rows per block
#define ITERS  4           // 1024 col4 / 256 threads

typedef float f32x4 __attribute__((ext_vector_type(4)));

__device__ __forceinline__ float l1d(const float4 a, const float4 b) {
    return fabsf(a.x - b.x) + fabsf(a.y - b.y) +
           fabsf(a.z - b.z) + fabsf(a.w - b.w);
}

__global__ __launch_bounds__(256) void matcher_cost_kernel(
    const float* __restrict__ logits,   // [rows, 2]
    const float* __restrict__ boxes,    // [rows, 4]
    const float* __restrict__ tgt,      // [4096, 4]
    const int*   __restrict__ ids,      // [4096]
    float* __restrict__ out)            // [rows, 4096]
{
    const int tid = threadIdx.x;
    const int r0  = blockIdx.x * RPB;

    // Per-row constants: box float4, nb = -p0, dp = p0 - p1.
    //   cost = l1 - (id ? p1 : p0) = l1 + nb + sel*dp,  sel = (id != 0)
    float4 bx[RPB];
    float  nb[RPB], dp[RPB];
#pragma unroll
    for (int r = 0; r < RPB; ++r) {
        const int row = r0 + r;
        bx[r] = reinterpret_cast<const float4*>(boxes)[row];
        const float p0 = 1.0f / (1.0f + __expf(-logits[row * 2 + 0]));
        const float p1 = 1.0f / (1.0f + __expf(-logits[row * 2 + 1]));
        nb[r] = -p0;
        dp[r] = p0 - p1;
    }

    const float4* __restrict__ tgt4 = reinterpret_cast<const float4*>(tgt);
    const int4*   __restrict__ ids4 = reinterpret_cast<const int4*>(ids);
    f32x4* __restrict__ out4 = reinterpret_cast<f32x4*>(out);

#pragma unroll
    for (int it = 0; it < ITERS; ++it) {
        const int jc = tid + it * 256;       // float4 column index
        const int jb = jc * 4;

        const int4 id4 = ids4[jc];
        const float sx = id4.x ? 1.0f : 0.0f;
        const float sy = id4.y ? 1.0f : 0.0f;
        const float sz = id4.z ? 1.0f : 0.0f;
        const float sw = id4.w ? 1.0f : 0.0f;

        const float4 t0 = tgt4[jb + 0];
        const float4 t1 = tgt4[jb + 1];
        const float4 t2 = tgt4[jb + 2];
        const float4 t3 = tgt4[jb + 3];

#pragma unroll
        for (int r = 0; r < RPB; ++r) {
            f32x4 res;
            res.x = fmaf(sx, dp[r], l1d(bx[r], t0) + nb[r]);
            res.y = fmaf(sy, dp[r], l1d(bx[r], t1) + nb[r]);
            res.z = fmaf(sz, dp[r], l1d(bx[r], t2) + nb[r]);
            res.w = fmaf(sw, dp[r], l1d(bx[r], t3) + nb[r]);
            // Zero-reuse output: nt store streams past L2, keeps the
            // column table resident.
            __builtin_nontemporal_store(res, &out4[(size_t)(r0 + r) * COLS4 + jc]);
        }
    }
}

extern "C" void kernel_launch(void* const* d_in, const int* in_sizes, int n_in,
                              void* d_out, int out_size, void* d_ws, size_t ws_size,
                              hipStream_t stream) {
    const float* logits = (const float*)d_in[0];   // pred_logits  [8,1024,2]
    const float* boxes  = (const float*)d_in[1];   // pred_boxes   [8,1024,4]
    const float* tgt    = (const float*)d_in[2];   // tgt_pts      [8,512,2,2]
    const int*   ids    = (const int*)d_in[3];     // tgt_labels   [8,512]
    float* out = (float*)d_out;

    const int rows = in_sizes[1] / 4;              // bs*Q = 8192
    matcher_cost_kernel<<<rows / RPB, 256, 0, stream>>>(logits, boxes, tgt, ids, out);
}

// Round 10
// 142.435 us; speedup vs baseline: 1.0445x; 1.0445x over previous
//
#include <hip/hip_runtime.h>
#include <hip/hip_bf16.h>
#include <math.h>

// HungarianMatcher cost matrix, round 10: RPB=8, PLAIN stores (nt removed).
// A/B vs round 8 (RPB=8 + nt, dur_us 148.7): the 134 MB output fits in the
// 256 MB Infinity Cache; the `nt` no-allocate hint may force HBM-rate
// drains. If plain stores let L3 absorb the stream, kernel time drops
// below the 21 us HBM write floor; if unchanged, we're at the floor and
// the residual dur_us is harness poison fills + graph gaps.
//
// Ladder (kernel-only est., dur_us minus ~85us ws-fill minus ~21us out-fill):
//   1 row/blk ~56 -> RPB=4 ~41 -> RPB=8+nt ~39 -> RPB=16+nt ~43 (null).
// Column re-read traffic saturated; reads are not the residual.

#define COLS   4096
#define COLS4  1024        // float4 columns
#define RPB    8           // rows per block
#define ITERS  4           // 1024 col4 / 256 threads

typedef float f32x4 __attribute__((ext_vector_type(4)));

__device__ __forceinline__ float l1d(const float4 a, const float4 b) {
    return fabsf(a.x - b.x) + fabsf(a.y - b.y) +
           fabsf(a.z - b.z) + fabsf(a.w - b.w);
}

__global__ __launch_bounds__(256) void matcher_cost_kernel(
    const float* __restrict__ logits,   // [rows, 2]
    const float* __restrict__ boxes,    // [rows, 4]
    const float* __restrict__ tgt,      // [4096, 4]
    const int*   __restrict__ ids,      // [4096]
    float* __restrict__ out)            // [rows, 4096]
{
    const int tid = threadIdx.x;
    const int r0  = blockIdx.x * RPB;

    // Per-row constants: box float4, nb = -p0, dp = p0 - p1.
    //   cost = l1 - (id ? p1 : p0) = l1 + nb + sel*dp,  sel = (id != 0)
    float4 bx[RPB];
    float  nb[RPB], dp[RPB];
#pragma unroll
    for (int r = 0; r < RPB; ++r) {
        const int row = r0 + r;
        bx[r] = reinterpret_cast<const float4*>(boxes)[row];
        const float p0 = 1.0f / (1.0f + __expf(-logits[row * 2 + 0]));
        const float p1 = 1.0f / (1.0f + __expf(-logits[row * 2 + 1]));
        nb[r] = -p0;
        dp[r] = p0 - p1;
    }

    const float4* __restrict__ tgt4 = reinterpret_cast<const float4*>(tgt);
    const int4*   __restrict__ ids4 = reinterpret_cast<const int4*>(ids);
    f32x4* __restrict__ out4 = reinterpret_cast<f32x4*>(out);

#pragma unroll
    for (int it = 0; it < ITERS; ++it) {
        const int jc = tid + it * 256;       // float4 column index
        const int jb = jc * 4;

        const int4 id4 = ids4[jc];
        const float sx = id4.x ? 1.0f : 0.0f;
        const float sy = id4.y ? 1.0f : 0.0f;
        const float sz = id4.z ? 1.0f : 0.0f;
        const float sw = id4.w ? 1.0f : 0.0f;

        const float4 t0 = tgt4[jb + 0];
        const float4 t1 = tgt4[jb + 1];
        const float4 t2 = tgt4[jb + 2];
        const float4 t3 = tgt4[jb + 3];

#pragma unroll
        for (int r = 0; r < RPB; ++r) {
            f32x4 res;
            res.x = fmaf(sx, dp[r], l1d(bx[r], t0) + nb[r]);
            res.y = fmaf(sy, dp[r], l1d(bx[r], t1) + nb[r]);
            res.z = fmaf(sz, dp[r], l1d(bx[r], t2) + nb[r]);
            res.w = fmaf(sw, dp[r], l1d(bx[r], t3) + nb[r]);
            // Plain store: let Infinity Cache absorb the write stream
            // (output fits in 256 MB L3).
            out4[(size_t)(r0 + r) * COLS4 + jc] = res;
        }
    }
}

extern "C" void kernel_launch(void* const* d_in, const int* in_sizes, int n_in,
                              void* d_out, int out_size, void* d_ws, size_t ws_size,
                              hipStream_t stream) {
    const float* logits = (const float*)d_in[0];   // pred_logits  [8,1024,2]
    const float* boxes  = (const float*)d_in[1];   // pred_boxes   [8,1024,4]
    const float* tgt    = (const float*)d_in[2];   // tgt_pts      [8,512,2,2]
    const int*   ids    = (const int*)d_in[3];     // tgt_labels   [8,512]
    float* out = (float*)d_out;

    const int rows = in_sizes[1] / 4;              // bs*Q = 8192
    matcher_cost_kernel<<<rows / RPB, 256, 0, stream>>>(logits, boxes, tgt, ids, out);
}